// Round 8
// baseline (207.359 us; speedup 1.0000x reference)
//
#include <hip/hip_runtime.h>

// B=8,H=8,S=1024,D=64 fp32 attention, raw-exp softmax, multiplicative key mask.
// Outputs: context[64,1024,64] then scores[64,1024,1024], both fp32.
// R8: three-way split.
//   k1 cvt_kv:  K->f16, V->f16 transposed (VT[bh][d][key])          (ws)
//   k2 pvrow_k: rowsums -> inv (ws, 256 KB) + unnormalized PV -> ctx
//   k3 scores_k: minimal streaming writer: QK MFMA, exp, *inv, nt store.
// k3 carries NO V/PV/LDS/barriers -> isolates the scores write stream.

typedef float    f32x4 __attribute__((ext_vector_type(4)));
typedef _Float16 f16x8 __attribute__((ext_vector_type(8)));
typedef _Float16 f16x4 __attribute__((ext_vector_type(4)));

#define MFMA32(A, B, C) __builtin_amdgcn_mfma_f32_16x16x32_f16((A), (B), (C), 0, 0, 0)
#define MFMA16(A, B, C) __builtin_amdgcn_mfma_f32_16x16x16f16((A), (B), (C), 0, 0, 0)

#define BHN 64
#define SEQ 1024
#define DIM 64

__device__ inline f16x8 cvt8(f32x4 a, f32x4 b) {
    f16x8 r;
    r[0] = (_Float16)a[0]; r[1] = (_Float16)a[1]; r[2] = (_Float16)a[2]; r[3] = (_Float16)a[3];
    r[4] = (_Float16)b[0]; r[5] = (_Float16)b[1]; r[6] = (_Float16)b[2]; r[7] = (_Float16)b[3];
    return r;
}

// ---- k1: K -> f16 same layout; V -> f16 transposed per (b,h): VT[bh][d][key].
__global__ __launch_bounds__(256)
void cvt_kv(const float* __restrict__ K, const float* __restrict__ V,
            _Float16* __restrict__ Kh, _Float16* __restrict__ VT)
{
    __shared__ _Float16 tile[128 * 65];
    const int bh = blockIdx.x >> 3;
    const int kc = blockIdx.x & 7;
    const int t  = threadIdx.x;
    const size_t base = ((size_t)bh * SEQ + (size_t)kc * 128) * DIM;

    for (int it = 0; it < 8; ++it) {
        int idx = it * 256 + t;
        int key = idx >> 4;
        int c4  = idx & 15;
        f32x4 kv = *(const f32x4*)(K + base + key * DIM + c4 * 4);
        f32x4 vv = *(const f32x4*)(V + base + key * DIM + c4 * 4);
        f16x4 kh4;
        kh4[0] = (_Float16)kv[0]; kh4[1] = (_Float16)kv[1];
        kh4[2] = (_Float16)kv[2]; kh4[3] = (_Float16)kv[3];
        *(f16x4*)(Kh + base + key * DIM + c4 * 4) = kh4;
        tile[key * 65 + c4 * 4 + 0] = (_Float16)vv[0];
        tile[key * 65 + c4 * 4 + 1] = (_Float16)vv[1];
        tile[key * 65 + c4 * 4 + 2] = (_Float16)vv[2];
        tile[key * 65 + c4 * 4 + 3] = (_Float16)vv[3];
    }
    __syncthreads();
    for (int it = 0; it < 4; ++it) {
        int idx = it * 256 + t;
        int dd = idx >> 4;
        int kg = idx & 15;
        f16x8 o;
        #pragma unroll
        for (int j = 0; j < 8; ++j) o[j] = tile[(kg * 8 + j) * 65 + dd];
        *(f16x8*)(VT + ((size_t)bh * DIM + dd) * SEQ + (size_t)kc * 128 + kg * 8) = o;
    }
}

// ---- k2: rowsum -> inv, unnormalized PV -> ctx. Grid 2048 (64 bh x 32-row
// q-blocks), 4 waves = key quarters. Swapped QK^T (lane: qrow=col, keys=g*4+i).
template <bool PRECONV>
__global__ __launch_bounds__(256, 4)
void pvrow_k(const float* __restrict__ Q, const float* __restrict__ K,
             const float* __restrict__ V, const float* __restrict__ mask,
             const _Float16* __restrict__ Kh, const _Float16* __restrict__ VT,
             float* __restrict__ invp, float* __restrict__ ctx)
{
    __shared__ float rs[4][2][16];
    __shared__ float cbuf[3][32][64];   // 24 KB

    const int bid = blockIdx.x;
    const int wg  = ((bid & 7) << 8) | (bid >> 3);   // XCD-bijective (2048 % 8 == 0)
    const int bh  = wg >> 5;
    const int qb  = wg & 31;
    const int b   = bh >> 3;
    const int w    = threadIdx.x >> 6;
    const int lane = threadIdx.x & 63;
    const int col  = lane & 15;
    const int g    = lane >> 4;
    const int q0   = qb * 32;
    const int kb   = w * 256;
    const float scale = 0.125f;

    f16x8 qf[2][2];
    {
        const float* qbase = Q + ((size_t)bh * SEQ + q0) * DIM;
        #pragma unroll
        for (int s = 0; s < 2; ++s)
            #pragma unroll
            for (int f = 0; f < 2; ++f) {
                const float* p = qbase + (s * 16 + col) * DIM + f * 32 + g * 8;
                qf[s][f] = cvt8(*(const f32x4*)p, *(const f32x4*)(p + 4));
            }
    }
    const float* mb = mask + (size_t)b * SEQ + kb;
    const _Float16* vtb = VT + (size_t)bh * DIM * SEQ + kb;

    float rsum[2] = {0.f, 0.f};
    f32x4 cacc[2][4];
    #pragma unroll
    for (int s = 0; s < 2; ++s)
        #pragma unroll
        for (int dt = 0; dt < 4; ++dt) cacc[s][dt] = (f32x4){0.f, 0.f, 0.f, 0.f};

    for (int kt = 0; kt < 16; ++kt) {
        f16x8 kf0, kf1;
        if (PRECONV) {
            const _Float16* kp = Kh + ((size_t)bh * SEQ + kb + kt * 16 + col) * DIM + g * 8;
            kf0 = *(const f16x8*)kp;
            kf1 = *(const f16x8*)(kp + 32);
        } else {
            const float* kp = K + ((size_t)bh * SEQ + kb + kt * 16 + col) * DIM + g * 8;
            kf0 = cvt8(*(const f32x4*)kp,        *(const f32x4*)(kp + 4));
            kf1 = cvt8(*(const f32x4*)(kp + 32), *(const f32x4*)(kp + 36));
        }
        f32x4 m4 = *(const f32x4*)(mb + kt * 16 + g * 4);

        f16x4 pf[2];
        #pragma unroll
        for (int s = 0; s < 2; ++s) {
            f32x4 acc = {0.f, 0.f, 0.f, 0.f};
            acc = MFMA32(kf0, qf[s][0], acc);
            acc = MFMA32(kf1, qf[s][1], acc);
            float e0 = __expf(acc[0] * scale) * m4[0];
            float e1 = __expf(acc[1] * scale) * m4[1];
            float e2 = __expf(acc[2] * scale) * m4[2];
            float e3 = __expf(acc[3] * scale) * m4[3];
            rsum[s] += e0 + e1 + e2 + e3;
            f16x4 ph;
            ph[0] = (_Float16)e0; ph[1] = (_Float16)e1;
            ph[2] = (_Float16)e2; ph[3] = (_Float16)e3;
            pf[s] = ph;
        }
        #pragma unroll
        for (int dt = 0; dt < 4; ++dt) {
            f16x4 vt;
            if (PRECONV) {
                vt = *(const f16x4*)(vtb + ((size_t)(dt * 16 + col)) * SEQ + kt * 16 + g * 4);
            } else {
                #pragma unroll
                for (int i = 0; i < 4; ++i)
                    vt[i] = (_Float16)V[((size_t)bh * SEQ + kb + kt * 16 + g * 4 + i) * DIM + dt * 16 + col];
            }
            cacc[0][dt] = MFMA16(vt, pf[0], cacc[0][dt]);
            cacc[1][dt] = MFMA16(vt, pf[1], cacc[1][dt]);
        }
    }

    // rowsum: reduce over the 4 lane-groups, then over the 4 waves (LDS)
    #pragma unroll
    for (int s = 0; s < 2; ++s) {
        float r = rsum[s];
        r += __shfl_xor(r, 16, 64);
        r += __shfl_xor(r, 32, 64);
        rsum[s] = r;
    }
    if (g == 0) {
        rs[w][0][col] = rsum[0];
        rs[w][1][col] = rsum[1];
    }
    __syncthreads();
    float inv[2];
    #pragma unroll
    for (int s = 0; s < 2; ++s)
        inv[s] = 1.0f / (rs[0][s][col] + rs[1][s][col] + rs[2][s][col] + rs[3][s][col] + 1e-8f);
    if (w == 0 && g == 0) {
        invp[(size_t)bh * SEQ + q0 + col]      = inv[0];
        invp[(size_t)bh * SEQ + q0 + 16 + col] = inv[1];
    }

    // normalize partial PV, combine across waves, write ctx
    #pragma unroll
    for (int s = 0; s < 2; ++s)
        #pragma unroll
        for (int dt = 0; dt < 4; ++dt)
            #pragma unroll
            for (int j = 0; j < 4; ++j) cacc[s][dt][j] *= inv[s];

    if (w != 0) {
        #pragma unroll
        for (int s = 0; s < 2; ++s)
            #pragma unroll
            for (int dt = 0; dt < 4; ++dt)
                #pragma unroll
                for (int j = 0; j < 4; ++j)
                    cbuf[w - 1][s * 16 + dt * 4 + j][lane] = cacc[s][dt][j];
    }
    __syncthreads();
    if (w == 0) {
        #pragma unroll
        for (int s = 0; s < 2; ++s)
            #pragma unroll
            for (int dt = 0; dt < 4; ++dt) {
                f32x4 r = cacc[s][dt];
                #pragma unroll
                for (int ww = 0; ww < 3; ++ww)
                    #pragma unroll
                    for (int j = 0; j < 4; ++j)
                        r[j] += cbuf[ww][s * 16 + dt * 4 + j][lane];
                *(f32x4*)(ctx + ((size_t)bh * SEQ + q0 + s * 16 + col) * DIM + dt * 16 + g * 4) = r;
            }
    }
}

// ---- k3: pure scores writer. Grid 1024 (64 bh x 16 q-blocks of 64 rows),
// 4 waves = q sub-tiles of 16 rows. Per iter: 3 L2-hot loads, 2 MFMA, 4 exp,
// 1 nt store. No LDS, no barriers, no V.
template <bool PRECONV>
__global__ __launch_bounds__(256)
void scores_k(const float* __restrict__ Q, const float* __restrict__ K,
              const float* __restrict__ mask, const _Float16* __restrict__ Kh,
              const float* __restrict__ invp, float* __restrict__ scores)
{
    const int bid = blockIdx.x;
    const int wg  = ((bid & 7) << 7) | (bid >> 3);   // XCD-bijective (1024 % 8 == 0)
    const int bh  = wg >> 4;
    const int qb  = wg & 15;
    const int b   = bh >> 3;
    const int w    = threadIdx.x >> 6;
    const int lane = threadIdx.x & 63;
    const int col  = lane & 15;
    const int g    = lane >> 4;
    const int qr0  = qb * 64 + w * 16;
    const float scale = 0.125f;

    f16x8 qf0, qf1;
    {
        const float* p = Q + ((size_t)bh * SEQ + qr0 + col) * DIM + g * 8;
        qf0 = cvt8(*(const f32x4*)p,        *(const f32x4*)(p + 4));
        qf1 = cvt8(*(const f32x4*)(p + 32), *(const f32x4*)(p + 36));
    }
    const float inv = invp[(size_t)bh * SEQ + qr0 + col];
    const float* mb = mask + (size_t)b * SEQ;
    float* srow = scores + ((size_t)bh * SEQ + qr0 + col) * SEQ;

    auto loadK = [&](int kt, f16x8& a, f16x8& c) {
        if (PRECONV) {
            const _Float16* kp = Kh + ((size_t)bh * SEQ + kt * 16 + col) * DIM + g * 8;
            a = *(const f16x8*)kp;
            c = *(const f16x8*)(kp + 32);
        } else {
            const float* kp = K + ((size_t)bh * SEQ + kt * 16 + col) * DIM + g * 8;
            a = cvt8(*(const f32x4*)kp,        *(const f32x4*)(kp + 4));
            c = cvt8(*(const f32x4*)(kp + 32), *(const f32x4*)(kp + 36));
        }
    };

    f16x8 k0, k1;
    f32x4 m4;
    loadK(0, k0, k1);
    m4 = *(const f32x4*)(mb + g * 4);

    for (int kt = 0; kt < 64; ++kt) {
        const int ktn = (kt + 1) & 63;
        f16x8 n0, n1;
        loadK(ktn, n0, n1);
        f32x4 nm = *(const f32x4*)(mb + ktn * 16 + g * 4);

        f32x4 acc = {0.f, 0.f, 0.f, 0.f};
        acc = MFMA32(k0, qf0, acc);
        acc = MFMA32(k1, qf1, acc);
        f32x4 o;
        o[0] = __expf(acc[0] * scale) * m4[0] * inv;
        o[1] = __expf(acc[1] * scale) * m4[1] * inv;
        o[2] = __expf(acc[2] * scale) * m4[2] * inv;
        o[3] = __expf(acc[3] * scale) * m4[3] * inv;
        __builtin_nontemporal_store(o, (f32x4*)(srow + kt * 16 + g * 4));

        k0 = n0; k1 = n1; m4 = nm;
    }
}

extern "C" void kernel_launch(void* const* d_in, const int* in_sizes, int n_in,
                              void* d_out, int out_size, void* d_ws, size_t ws_size,
                              hipStream_t stream)
{
    const float* Q    = (const float*)d_in[0];
    const float* K    = (const float*)d_in[1];
    const float* V    = (const float*)d_in[2];
    const float* mask = (const float*)d_in[3];
    float* ctx    = (float*)d_out;
    float* scores = ctx + (size_t)BHN * SEQ * DIM;

    const size_t elems = (size_t)BHN * SEQ * DIM;                 // 4,194,304
    const size_t inv_bytes = (size_t)BHN * SEQ * sizeof(float);   // 256 KB
    const size_t need = elems * 2 * sizeof(_Float16) + inv_bytes; // ~16.25 MB

    if (ws_size >= need) {
        _Float16* Kh   = (_Float16*)d_ws;
        _Float16* VT   = Kh + elems;
        float*    invp = (float*)(VT + elems);
        cvt_kv<<<512, 256, 0, stream>>>(K, V, Kh, VT);
        pvrow_k<true><<<2048, 256, 0, stream>>>(Q, K, V, mask, Kh, VT, invp, ctx);
        scores_k<true><<<1024, 256, 0, stream>>>(Q, K, mask, Kh, invp, scores);
    } else {
        float* invp = (float*)d_ws;   // needs only 256 KB
        pvrow_k<false><<<2048, 256, 0, stream>>>(Q, K, V, mask, nullptr, nullptr, invp, ctx);
        scores_k<false><<<1024, 256, 0, stream>>>(Q, K, mask, nullptr, invp, scores);
    }
}

// Round 9
// 100.863 us; speedup vs baseline: 2.0558x; 2.0558x over previous
//
#include <hip/hip_runtime.h>

// B=8,H=8,S=1024,D=64 fp32 attention, raw-exp softmax, multiplicative key mask.
// Outputs: context[64,1024,64] then scores[64,1024,1024], both fp32.
// R9 = R4 (best: 135 us) + two load-path fixes in the compute loop:
//   (1) VTP repack: per-kt V fragments are 2x16B coalesced loads (was 4x8B).
//   (2) one-ahead software prefetch of all 5 loads per kt.
// Stores stay isolated in the barrier-separated flush phase (LDS-only deps;
// avoids the shared-vmcnt load-after-store throttle seen in in-loop-store
// kernels R7/R8). nt stores kept (R4 135 vs R6 plain 150).

typedef float    f32x4 __attribute__((ext_vector_type(4)));
typedef _Float16 f16x8 __attribute__((ext_vector_type(8)));
typedef _Float16 f16x4 __attribute__((ext_vector_type(4)));

#define MFMA32(A, B, C) __builtin_amdgcn_mfma_f32_16x16x32_f16((A), (B), (C), 0, 0, 0)
#define MFMA16(A, B, C) __builtin_amdgcn_mfma_f32_16x16x16f16((A), (B), (C), 0, 0, 0)

#define BHN 64
#define SEQ 1024
#define DIM 64

__device__ inline f16x8 cvt8(f32x4 a, f32x4 b) {
    f16x8 r;
    r[0] = (_Float16)a[0]; r[1] = (_Float16)a[1]; r[2] = (_Float16)a[2]; r[3] = (_Float16)a[3];
    r[4] = (_Float16)b[0]; r[5] = (_Float16)b[1]; r[6] = (_Float16)b[2]; r[7] = (_Float16)b[3];
    return r;
}

// Pre-pass: K -> f16 same layout; V -> f16 repacked for PV:
// VTP[bh][ktg][lane][e], e = dt*4+i : V[bh][ktg*16 + (lane>>4)*4 + i][dt*16 + (lane&15)]
// -> per (kt, lane) the 16 f16 a lane needs are contiguous (two 16-B loads),
//    and the wave's 2 KB block is contiguous and lane-ordered (coalesced).
__global__ __launch_bounds__(256)
void cvt_kv(const float* __restrict__ K, const float* __restrict__ V,
            _Float16* __restrict__ Kh, _Float16* __restrict__ VTP)
{
    __shared__ _Float16 tile[128 * 65];
    const int bh = blockIdx.x >> 3;
    const int kc = blockIdx.x & 7;
    const int t  = threadIdx.x;
    const size_t base = ((size_t)bh * SEQ + (size_t)kc * 128) * DIM;

    for (int it = 0; it < 8; ++it) {
        int idx = it * 256 + t;
        int key = idx >> 4;
        int c4  = idx & 15;
        f32x4 kv = *(const f32x4*)(K + base + key * DIM + c4 * 4);
        f32x4 vv = *(const f32x4*)(V + base + key * DIM + c4 * 4);
        f16x4 kh4;
        kh4[0] = (_Float16)kv[0]; kh4[1] = (_Float16)kv[1];
        kh4[2] = (_Float16)kv[2]; kh4[3] = (_Float16)kv[3];
        *(f16x4*)(Kh + base + key * DIM + c4 * 4) = kh4;
        tile[key * 65 + c4 * 4 + 0] = (_Float16)vv[0];
        tile[key * 65 + c4 * 4 + 1] = (_Float16)vv[1];
        tile[key * 65 + c4 * 4 + 2] = (_Float16)vv[2];
        tile[key * 65 + c4 * 4 + 3] = (_Float16)vv[3];
    }
    __syncthreads();
    // 8 kt-tiles x 64 lanes x 4 f16x4-chunks = 2048 chunks
    for (int it = 0; it < 8; ++it) {
        int flat = it * 256 + t;
        int ktl  = flat >> 8;          // 0..7
        int rem  = flat & 255;
        int l    = rem >> 2;           // lane 0..63
        int c    = rem & 3;            // dt 0..3
        f16x4 o;
        #pragma unroll
        for (int j = 0; j < 4; ++j)
            o[j] = tile[(ktl * 16 + ((l >> 4) << 2) + j) * 65 + c * 16 + (l & 15)];
        *(f16x4*)(VTP + (((size_t)bh * 64 + kc * 8 + ktl) * 64 + l) * 16 + c * 4) = o;
    }
}

// Main kernel. 2048 blocks x 256 thr. Block = 32 q-rows of one (b,h), all keys.
// Wave w owns key quarter [w*256, ...). Swapped QK^T: lane qrow = lane&15,
// keys = (lane>>4)*4+i. E staged f16 in 64 KB LDS (XOR-swizzled granules),
// flush phase: nt contiguous 1-KB row stores. Epilogue: PV combine via LDS.
template <bool PRECONV>
__global__ __launch_bounds__(256, 2)
void attn_main(const float* __restrict__ Q, const float* __restrict__ K,
               const float* __restrict__ V, const float* __restrict__ mask,
               const _Float16* __restrict__ Kh, const _Float16* __restrict__ VTP,
               float* __restrict__ ctx, float* __restrict__ scores)
{
    __shared__ _Float16 Et[32 * 1024];   // 64 KB

    const int bid = blockIdx.x;
    const int wg  = ((bid & 7) << 8) | (bid >> 3);  // XCD-bijective (2048 % 8 == 0)
    const int bh  = wg >> 5;
    const int qb  = wg & 31;
    const int b   = bh >> 3;
    const int w    = threadIdx.x >> 6;   // key quarter
    const int lane = threadIdx.x & 63;
    const int col  = lane & 15;
    const int g    = lane >> 4;
    const int q0   = qb * 32;
    const int kb   = w * 256;
    const float scale = 0.125f;
    char* EtB = (char*)Et;

    // ---- Q fragments: qf[s][f] : Q[q0+s*16+col][f*32 + g*8 .. +7]
    f16x8 qf[2][2];
    {
        const float* qbase = Q + ((size_t)bh * SEQ + q0) * DIM;
        #pragma unroll
        for (int s = 0; s < 2; ++s)
            #pragma unroll
            for (int f = 0; f < 2; ++f) {
                const float* p = qbase + (s * 16 + col) * DIM + f * 32 + g * 8;
                qf[s][f] = cvt8(*(const f32x4*)p, *(const f32x4*)(p + 4));
            }
    }
    const float* mb = mask + (size_t)b * SEQ + kb;
    const _Float16* kbase = Kh + ((size_t)bh * SEQ + kb + col) * DIM + g * 8;
    const _Float16* vtpb  = VTP + (((size_t)bh * 64 + w * 16) * 64 + lane) * 16;

    f32x4 cacc[2][4];
    #pragma unroll
    for (int s = 0; s < 2; ++s)
        #pragma unroll
        for (int dt = 0; dt < 4; ++dt) cacc[s][dt] = (f32x4){0.f, 0.f, 0.f, 0.f};

    // ---- single pass, one-ahead prefetch of all 5 loads
    f16x8 k0, k1, va, vb;
    f32x4 m4;
    if (PRECONV) {
        k0 = *(const f16x8*)(kbase);
        k1 = *(const f16x8*)(kbase + 32);
        va = *(const f16x8*)(vtpb);
        vb = *(const f16x8*)(vtpb + 8);
    } else {
        const float* kp = K + ((size_t)bh * SEQ + kb + col) * DIM + g * 8;
        k0 = cvt8(*(const f32x4*)kp,        *(const f32x4*)(kp + 4));
        k1 = cvt8(*(const f32x4*)(kp + 32), *(const f32x4*)(kp + 36));
        #pragma unroll
        for (int e = 0; e < 8; ++e) {
            va[e] = (_Float16)V[((size_t)bh * SEQ + kb + g * 4 + (e & 3)) * DIM + (e >> 2) * 16 + col];
            vb[e] = (_Float16)V[((size_t)bh * SEQ + kb + g * 4 + (e & 3)) * DIM + (2 + (e >> 2)) * 16 + col];
        }
    }
    m4 = *(const f32x4*)(mb + g * 4);

    for (int kt = 0; kt < 16; ++kt) {
        const int ktn = (kt + 1) & 15;
        f16x8 n0, n1, nva, nvb;
        if (PRECONV) {
            n0  = *(const f16x8*)(kbase + (size_t)ktn * 16 * DIM);
            n1  = *(const f16x8*)(kbase + (size_t)ktn * 16 * DIM + 32);
            nva = *(const f16x8*)(vtpb + (size_t)ktn * 64 * 16);
            nvb = *(const f16x8*)(vtpb + (size_t)ktn * 64 * 16 + 8);
        } else {
            const float* kp = K + ((size_t)bh * SEQ + kb + ktn * 16 + col) * DIM + g * 8;
            n0 = cvt8(*(const f32x4*)kp,        *(const f32x4*)(kp + 4));
            n1 = cvt8(*(const f32x4*)(kp + 32), *(const f32x4*)(kp + 36));
            #pragma unroll
            for (int e = 0; e < 8; ++e) {
                nva[e] = (_Float16)V[((size_t)bh * SEQ + kb + ktn * 16 + g * 4 + (e & 3)) * DIM + (e >> 2) * 16 + col];
                nvb[e] = (_Float16)V[((size_t)bh * SEQ + kb + ktn * 16 + g * 4 + (e & 3)) * DIM + (2 + (e >> 2)) * 16 + col];
            }
        }
        f32x4 nm = *(const f32x4*)(mb + ktn * 16 + g * 4);

        f16x4 pf[2];
        #pragma unroll
        for (int s = 0; s < 2; ++s) {
            f32x4 acc = {0.f, 0.f, 0.f, 0.f};
            acc = MFMA32(k0, qf[s][0], acc);
            acc = MFMA32(k1, qf[s][1], acc);
            f16x4 eh;
            eh[0] = (_Float16)(__expf(acc[0] * scale) * m4[0]);
            eh[1] = (_Float16)(__expf(acc[1] * scale) * m4[1]);
            eh[2] = (_Float16)(__expf(acc[2] * scale) * m4[2]);
            eh[3] = (_Float16)(__expf(acc[3] * scale) * m4[3]);
            pf[s] = eh;
            const int row = s * 16 + col;
            const int kg  = (w * 64 + kt * 4 + g) ^ ((row & 3) << 2);
            *(f16x4*)(EtB + row * 2048 + kg * 8) = eh;
        }
        {
            f16x4 vt0 = __builtin_shufflevector(va, va, 0, 1, 2, 3);
            f16x4 vt1 = __builtin_shufflevector(va, va, 4, 5, 6, 7);
            f16x4 vt2 = __builtin_shufflevector(vb, vb, 0, 1, 2, 3);
            f16x4 vt3 = __builtin_shufflevector(vb, vb, 4, 5, 6, 7);
            cacc[0][0] = MFMA16(vt0, pf[0], cacc[0][0]);
            cacc[1][0] = MFMA16(vt0, pf[1], cacc[1][0]);
            cacc[0][1] = MFMA16(vt1, pf[0], cacc[0][1]);
            cacc[1][1] = MFMA16(vt1, pf[1], cacc[1][1]);
            cacc[0][2] = MFMA16(vt2, pf[0], cacc[0][2]);
            cacc[1][2] = MFMA16(vt2, pf[1], cacc[1][2]);
            cacc[0][3] = MFMA16(vt3, pf[0], cacc[0][3]);
            cacc[1][3] = MFMA16(vt3, pf[1], cacc[1][3]);
        }
        k0 = n0; k1 = n1; va = nva; vb = nvb; m4 = nm;
    }

    __syncthreads();

    // ---- flush phase (UNCHANGED from R4): wave w rows w*8..w*8+7; rowsum from
    // tile, scale, nt store 4 x 1-KB contiguous per row. Only LDS deps here.
    const int r0 = w * 8;
    float* srow = scores + ((size_t)bh * SEQ + q0) * SEQ;
    for (int j = 0; j < 8; ++j) {
        const int r = r0 + j;
        f16x4 ev[4];
        #pragma unroll
        for (int q = 0; q < 4; ++q) {
            const int kg = (q * 64 + lane) ^ ((r & 3) << 2);
            ev[q] = *(const f16x4*)(EtB + r * 2048 + kg * 8);
        }
        float s0 = 0.f;
        #pragma unroll
        for (int q = 0; q < 4; ++q)
            #pragma unroll
            for (int i = 0; i < 4; ++i) s0 += (float)ev[q][i];
        #pragma unroll
        for (int off = 1; off < 64; off <<= 1) s0 += __shfl_xor(s0, off, 64);
        const float invr = 1.0f / (s0 + 1e-8f);
        float* dst = srow + (size_t)r * SEQ + lane * 4;
        #pragma unroll
        for (int q = 0; q < 4; ++q) {
            f32x4 o;
            o[0] = (float)ev[q][0] * invr;
            o[1] = (float)ev[q][1] * invr;
            o[2] = (float)ev[q][2] * invr;
            o[3] = (float)ev[q][3] * invr;
            __builtin_nontemporal_store(o, (f32x4*)(dst + q * 256));
        }
        if (lane == 0) *(float*)(EtB + r0 * 2048 + j * 4) = invr;
    }

    __syncthreads();

    // ---- PV combine epilogue (UNCHANGED from R4)
    if (w != 0) {
        float* dump = (float*)(EtB + (1 + (w - 1) * 8) * 2048);
        #pragma unroll
        for (int s = 0; s < 2; ++s)
            #pragma unroll
            for (int dt = 0; dt < 4; ++dt)
                #pragma unroll
                for (int i = 0; i < 4; ++i)
                    dump[((s * 4 + dt) * 4 + i) * 64 + lane] = cacc[s][dt][i];
    }
    __syncthreads();
    if (w == 0) {
        #pragma unroll
        for (int s = 0; s < 2; ++s) {
            const int qrow = s * 16 + col;
            const float invr = *(const float*)(EtB + (qrow >> 3) * 8 * 2048 + (qrow & 7) * 4);
            #pragma unroll
            for (int dt = 0; dt < 4; ++dt) {
                f32x4 r = cacc[s][dt];
                #pragma unroll
                for (int ww = 1; ww < 4; ++ww) {
                    const float* dump = (const float*)(EtB + (1 + (ww - 1) * 8) * 2048);
                    #pragma unroll
                    for (int i = 0; i < 4; ++i)
                        r[i] += dump[((s * 4 + dt) * 4 + i) * 64 + lane];
                }
                r[0] *= invr; r[1] *= invr; r[2] *= invr; r[3] *= invr;
                *(f32x4*)(ctx + ((size_t)bh * SEQ + q0 + qrow) * DIM + dt * 16 + g * 4) = r;
            }
        }
    }
}

extern "C" void kernel_launch(void* const* d_in, const int* in_sizes, int n_in,
                              void* d_out, int out_size, void* d_ws, size_t ws_size,
                              hipStream_t stream)
{
    const float* Q    = (const float*)d_in[0];
    const float* K    = (const float*)d_in[1];
    const float* V    = (const float*)d_in[2];
    const float* mask = (const float*)d_in[3];
    float* ctx    = (float*)d_out;
    float* scores = ctx + (size_t)BHN * SEQ * DIM;

    const size_t elems = (size_t)BHN * SEQ * DIM;       // 4,194,304
    const size_t need  = elems * 2 * sizeof(_Float16);  // Kh + VTP = 16 MB
    if (ws_size >= need) {
        _Float16* Kh  = (_Float16*)d_ws;
        _Float16* VTP = Kh + elems;
        cvt_kv<<<512, 256, 0, stream>>>(K, V, Kh, VTP);
        attn_main<true><<<2048, 256, 0, stream>>>(Q, K, V, mask, Kh, VTP, ctx, scores);
    } else {
        attn_main<false><<<2048, 256, 0, stream>>>(Q, K, V, mask, nullptr, nullptr, ctx, scores);
    }
}